// Round 6
// 3644.058 us; speedup vs baseline: 1.0155x; 1.0155x over previous
//
#include <hip/hip_runtime.h>

typedef unsigned short u16;
typedef __attribute__((ext_vector_type(8))) short short8;
typedef __attribute__((ext_vector_type(4))) float f32x4;
typedef __attribute__((ext_vector_type(2))) float f32x2;

#define S_ 512
#define I_ 512
#define H_ 1024
#define B_ 32
#define G_ 4096   // 4*H
#define WROW 1536 // I+H
#define CH_ 128
#define CHLOG_ 7
#define NREC 64
#define NWRK 192  // grid = 256 total: unconditional co-residency (1 block/CU)

__device__ __forceinline__ u16 f2b(float f){ union{float f;unsigned u;}c; c.f=f; unsigned u=c.u; return (u16)((u + 0x7FFFu + ((u>>16)&1u))>>16); }

// trunc-pack two fp32 into two bf16 lanes (verified pattern; NOT v_perm)
__device__ __forceinline__ unsigned pk2(float a, float b){
  union{float f;unsigned u;} x, y; x.f=a; y.f=b;
  return (x.u>>16) | (y.u & 0xffff0000u);
}
__device__ __forceinline__ short8 cvt8(const float* __restrict__ p){
  f32x4 a = *(const f32x4*)p;
  f32x4 b = *(const f32x4*)(p+4);
  union{unsigned u[4]; short8 s;} r;
  r.u[0]=pk2(a[0],a[1]); r.u[1]=pk2(a[2],a[3]);
  r.u[2]=pk2(b[0],b[1]); r.u[3]=pk2(b[2],b[3]);
  return r.s;
}
__device__ __forceinline__ f32x4 mfma16(short8 a, short8 b, f32x4 c){
  return __builtin_amdgcn_mfma_f32_16x16x32_bf16(a,b,c,0,0,0);
}
__device__ __forceinline__ float sigf(float x){ return 1.0f/(1.0f+__expf(-x)); }
__device__ __forceinline__ float tanhfast(float x){ return 1.0f - 2.0f/(__expf(2.0f*x)+1.0f); }

// ---------------------------------------------------------------------------
// Standalone k_xg (PROLOGUE only, chunk 0) — verbatim verified kernel.
// xg[sl][g][b] = sum_i x[b][t0+sl][i]*W[g][i] + bias[g]
// ---------------------------------------------------------------------------
__global__ __launch_bounds__(256,2) void k_xg(
    const float* __restrict__ x,
    const float* __restrict__ Wf, const float* __restrict__ Wi,
    const float* __restrict__ Wo, const float* __restrict__ Wc,
    const float* __restrict__ bfp, const float* __restrict__ bip,
    const float* __restrict__ bop, const float* __restrict__ bcp,
    float* __restrict__ xg, int t0)
{
  const int gt = blockIdx.x;
  const int sg = blockIdx.y;
  const int wv = threadIdx.x>>6;
  const int ln = threadIdx.x&63;
  const int n16 = ln&15, qd = ln>>4;
  const int g0 = gt*64 + wv*16;
  const int q = g0>>10, j0 = g0&1023;
  const float* W  = (q==0)?Wf:(q==1)?Wi:(q==2)?Wo:Wc;
  const float* bb = (q==0)?bfp:(q==1)?bip:(q==2)?bop:bcp;

  short8 Bw[16];
  {
    const float* wr = W + (size_t)(j0+n16)*WROW + qd*8;
    #pragma unroll
    for(int kt=0;kt<16;++kt) Bw[kt] = cvt8(wr + kt*32);
  }
  const float bv = bb[j0+n16];

  for(int si=0; si<8; ++si){
    const int sl = sg*8 + si;
    const int s  = t0 + sl;
    const float* xp = x + (size_t)n16*(S_*I_) + (size_t)s*I_ + qd*8;
    f32x4 a0={0,0,0,0}, a1={0,0,0,0};
    #pragma unroll
    for(int kt=0;kt<16;++kt){
      short8 A0 = cvt8(xp + kt*32);
      short8 A1 = cvt8(xp + (size_t)16*(S_*I_) + kt*32);
      a0 = mfma16(A0, Bw[kt], a0);
      a1 = mfma16(A1, Bw[kt], a1);
    }
    float* op = xg + ((size_t)sl*G_ + g0 + n16)*B_ + qd*4;
    f32x4 o0, o1;
    #pragma unroll
    for(int r=0;r<4;++r){ o0[r]=a0[r]+bv; o1[r]=a1[r]+bv; }
    *(f32x4*)op = o0;
    *(f32x4*)(op+16) = o1;
  }
}

// ---------------------------------------------------------------------------
// Standalone k_out (EPILOGUE only, last chunk) — verbatim verified kernel.
// ---------------------------------------------------------------------------
__global__ __launch_bounds__(256,2) void k_out(
  const u16* __restrict__ hs,
  const float* __restrict__ ow,
  const float* __restrict__ obp,
  float* __restrict__ out, int t0, int chlog)
{
  const int bst = blockIdx.x;
  const int ot  = blockIdx.y;
  const int wv = threadIdx.x>>6;
  const int ln = threadIdx.x&63;
  const int n16 = ln&15, qd = ln>>4;
  const int bs0 = bst*64 + wv*16 + n16;
  const u16* bp   = hs + (size_t)bs0*H_ + qd*8;
  const float* ap = ow + (size_t)(ot*64 + n16)*H_ + qd*8;
  f32x4 acc[4];
  #pragma unroll
  for(int m=0;m<4;++m) acc[m]=(f32x4){0.f,0.f,0.f,0.f};
  #pragma unroll 4
  for(int kt=0;kt<32;++kt){
    short8 Bfr = *(const short8*)(bp + kt*32);
    #pragma unroll
    for(int m=0;m<4;++m){
      short8 Afr = cvt8(ap + (size_t)m*16*H_ + kt*32);
      acc[m] = mfma16(Afr, Bfr, acc[m]);
    }
  }
  const int b  = bs0 >> chlog;
  const int sl = bs0 & ((1<<chlog)-1);
  float* orow = out + ((size_t)b*S_ + t0 + sl)*512;
  #pragma unroll
  for(int m=0;m<4;++m){
    const int o0 = ot*64 + m*16 + qd*4;
    f32x4 ov;
    #pragma unroll
    for(int r=0;r<4;++r) ov[r] = acc[m][r] + obp[o0+r];
    *(f32x4*)(orow + o0) = ov;
  }
}

// ---------------------------------------------------------------------------
// k_fused: cooperative dispatch for chunk c. Grid 256 (64 rec + 192 workers)
// — 1 block/CU, co-residency unconditional (same regime as the verified R0
// coop launches).
//   blocks 0..63    : R0-verified k_rec body (reads xg_cur, writes hs_cur).
//     Deltas vs R0 (3, enumerated): (1) tl==0 h-carry reads
//     hs_prev[b][CH_-1][:] instead of hprev (bit-identical data);
//     (2) the hprev chunk-carry store is dropped; (3) xg arg renamed xg_cur.
//   blocks 64..255  : workers. xg tiles for chunk c+1 (k_xg body verbatim,
//     reads only input x, writes xg_next) and out tiles for chunk c-1
//     (k_out body verbatim, reads hs_prev written LAST dispatch).
//   NO intra-dispatch rec<->worker dependency: all worker inputs/outputs
//   cross dispatch boundaries (cache flush/invalidate — the same mechanism
//   the verified kernel already relies on for hprev/cbuf/xg handoff).
// ---------------------------------------------------------------------------
__global__ __launch_bounds__(256,1) void k_fused(
  const float* __restrict__ x,
  const float* __restrict__ Wf, const float* __restrict__ Wi,
  const float* __restrict__ Wo, const float* __restrict__ Wc,
  const float* __restrict__ bfp, const float* __restrict__ bip,
  const float* __restrict__ bop, const float* __restrict__ bcp,
  const float* __restrict__ ow, const float* __restrict__ obp,
  const float* __restrict__ xg_cur,  // [CH_][4096][32] this chunk
  float* __restrict__ xg_next,       // next chunk (null on last)
  const u16* __restrict__ hs_prev,   // [32][CH_][1024] prev chunk (carry + out src)
  u16* __restrict__ hs_cur,          // [32][CH_][1024] this chunk
  float* __restrict__ hfin, float* __restrict__ cfin,
  float* __restrict__ cbuf,          // [32][1024] f32 c carry
  unsigned* __restrict__ flags,      // 64 x u32, 128B apart, monotone abs-t
  float* __restrict__ out,
  int t0, int do_out)
{
  const int bid = blockIdx.x;
  const int tid = threadIdx.x;
  __shared__ float pbuf[4][4][16][38]; // rec only

  if (bid < NREC){
    // ---------------- recurrence (verified body) ----------------
    const int h0  = bid*16;
    const int kw  = tid>>6;
    const int ln  = tid&63;
    const int n16 = ln&15, qd = ln>>4;

    short8 Bf[4][8];
    {
      const int kcol = 512 + kw*256 + qd*8;
      const float* w0 = Wf + (size_t)(h0+n16)*WROW + kcol;
      const float* w1 = Wi + (size_t)(h0+n16)*WROW + kcol;
      const float* w2 = Wo + (size_t)(h0+n16)*WROW + kcol;
      const float* w3 = Wc + (size_t)(h0+n16)*WROW + kcol;
      #pragma unroll
      for(int k=0;k<8;++k){
        Bf[0][k] = cvt8(w0 + k*32);
        Bf[1][k] = cvt8(w1 + k*32);
        Bf[2][k] = cvt8(w2 + k*32);
        Bf[3][k] = cvt8(w3 + k*32);
      }
    }
    const int ub  = tid>>3;
    const int hi0 = (tid&7)*2;
    f32x2 c01 = *(const f32x2*)(cbuf + (size_t)ub*H_ + h0 + hi0);

    for(int tl=0; tl<CH_; ++tl){
      const int t = t0 + tl;
      float xv[2][4];
      {
        const float* xp = xg_cur + ((size_t)tl*G_ + h0 + hi0)*B_ + ub;
        #pragma unroll
        for(int q=0;q<4;++q){
          xv[0][q] = xp[(size_t)q*1024*B_];
          xv[1][q] = xp[(size_t)q*1024*B_ + B_];
        }
      }
      if (t>0){
        if (tid < 64){
          const unsigned goal = (unsigned)t;
          unsigned v;
          do {
            v = __hip_atomic_load(flags + (tid<<5), __ATOMIC_RELAXED, __HIP_MEMORY_SCOPE_AGENT);
            if (__ballot(v < goal) == 0ull) break;
            __builtin_amdgcn_s_sleep(1);
          } while (true);
          // no fence needed: hs[tl-1] lines are first-touch-after-flag
        }
        __syncthreads();
      }
      const u16* hbase; size_t bstride;
      if (tl==0){ hbase = hs_prev + (size_t)(CH_-1)*H_; bstride = (size_t)CH_*H_; }
      else      { hbase = hs_cur  + (size_t)(tl-1)*H_;  bstride = (size_t)CH_*H_; }
      const int kcolq = kw*256 + qd*8;
      const u16* hp0 = hbase + (size_t)n16*bstride      + kcolq;
      const u16* hp1 = hbase + (size_t)(16+n16)*bstride + kcolq;
      f32x4 acc[2][4];
      #pragma unroll
      for(int m=0;m<2;++m)
        #pragma unroll
        for(int q=0;q<4;++q) acc[m][q]=(f32x4){0.f,0.f,0.f,0.f};
      #pragma unroll
      for(int k=0;k<8;++k){
        short8 A0 = *(const short8*)(hp0 + k*32);
        short8 A1 = *(const short8*)(hp1 + k*32);
        #pragma unroll
        for(int q=0;q<4;++q){
          acc[0][q] = mfma16(A0, Bf[q][k], acc[0][q]);
          acc[1][q] = mfma16(A1, Bf[q][k], acc[1][q]);
        }
      }
      #pragma unroll
      for(int m=0;m<2;++m)
        #pragma unroll
        for(int q=0;q<4;++q){
          float* dst = &pbuf[kw][q][n16][m*16 + qd*4];
          *(f32x2*)dst       = (f32x2){acc[m][q][0], acc[m][q][1]};
          *(f32x2*)(dst + 2) = (f32x2){acc[m][q][2], acc[m][q][3]};
        }
      __syncthreads();
      float g[2][4];
      #pragma unroll
      for(int e=0;e<2;++e){
        #pragma unroll
        for(int q=0;q<4;++q){
          g[e][q] = xv[e][q] + pbuf[0][q][hi0+e][ub] + pbuf[1][q][hi0+e][ub]
                             + pbuf[2][q][hi0+e][ub] + pbuf[3][q][hi0+e][ub];
        }
      }
      float hv[2], cn[2];
      #pragma unroll
      for(int e=0;e<2;++e){
        float fg = sigf(g[e][0]);
        float ig = sigf(g[e][1]);
        float og = sigf(g[e][2]);
        float ch = tanhfast(g[e][3]);
        cn[e] = fg*c01[e] + ig*ch;
        hv[e] = og*tanhfast(cn[e]);
        c01[e] = cn[e];
      }
      const unsigned hpk = (unsigned)f2b(hv[0]) | ((unsigned)f2b(hv[1])<<16);
      unsigned* hw = (unsigned*)(hs_cur + ((size_t)ub*CH_ + tl)*H_ + h0 + hi0);
      __hip_atomic_store(hw, hpk, __ATOMIC_RELAXED, __HIP_MEMORY_SCOPE_AGENT);
      if (t==511){
        *(f32x2*)(hfin + (size_t)ub*H_ + h0 + hi0) = (f32x2){hv[0], hv[1]};
        *(f32x2*)(cfin + (size_t)ub*H_ + h0 + hi0) = (f32x2){cn[0], cn[1]};
      }
      if (tl==CH_-1)
        *(f32x2*)(cbuf + (size_t)ub*H_ + h0 + hi0) = c01;
      __syncthreads();              // vmcnt(0): hs stores ack'd at LLC
      if (tid==0)
        __hip_atomic_store(flags + (bid<<5), (unsigned)(t+1),
                           __ATOMIC_RELAXED, __HIP_MEMORY_SCOPE_AGENT);
    }
    return;
  }

  // ---------------- workers ----------------
  const int w  = bid - NREC;
  const int N1 = xg_next ? 1024 : 0;   // 64 gt x 16 sg tiles (chunk c+1)
  const int N2 = do_out  ? 512  : 0;   // 64 bst x 8 ot tiles (chunk c-1)
  for (int tau = w; tau < N1 + N2; tau += NWRK){
    if (tau < N1){
      // --- k_xg tile, verbatim body; target chunk t0+CH_ ---
      const int gt = tau & 63, sg = tau >> 6;
      const int wv = tid>>6;
      const int ln = tid&63;
      const int n16 = ln&15, qd = ln>>4;
      const int g0 = gt*64 + wv*16;
      const int q = g0>>10, j0 = g0&1023;
      const float* W  = (q==0)?Wf:(q==1)?Wi:(q==2)?Wo:Wc;
      const float* bb = (q==0)?bfp:(q==1)?bip:(q==2)?bop:bcp;
      short8 Bw[16];
      {
        const float* wr = W + (size_t)(j0+n16)*WROW + qd*8;
        #pragma unroll
        for(int kt=0;kt<16;++kt) Bw[kt] = cvt8(wr + kt*32);
      }
      const float bv = bb[j0+n16];
      for(int si=0; si<8; ++si){
        const int sl = sg*8 + si;
        const int s  = t0 + CH_ + sl;
        const float* xp = x + (size_t)n16*(S_*I_) + (size_t)s*I_ + qd*8;
        f32x4 a0={0,0,0,0}, a1={0,0,0,0};
        #pragma unroll
        for(int kt=0;kt<16;++kt){
          short8 A0 = cvt8(xp + kt*32);
          short8 A1 = cvt8(xp + (size_t)16*(S_*I_) + kt*32);
          a0 = mfma16(A0, Bw[kt], a0);
          a1 = mfma16(A1, Bw[kt], a1);
        }
        float* op = xg_next + ((size_t)sl*G_ + g0 + n16)*B_ + qd*4;
        f32x4 o0, o1;
        #pragma unroll
        for(int r=0;r<4;++r){ o0[r]=a0[r]+bv; o1[r]=a1[r]+bv; }
        *(f32x4*)op = o0;
        *(f32x4*)(op+16) = o1;
      }
    } else {
      // --- k_out tile, verbatim body; source chunk t0-CH_ ---
      const int t2 = tau - N1;
      const int bst = t2 & 63, ot = t2 >> 6;
      const int wv = tid>>6;
      const int ln = tid&63;
      const int n16 = ln&15, qd = ln>>4;
      const int bs0 = bst*64 + wv*16 + n16;
      const u16* bp   = hs_prev + (size_t)bs0*H_ + qd*8;
      const float* ap = ow + (size_t)(ot*64 + n16)*H_ + qd*8;
      f32x4 acc[4];
      #pragma unroll
      for(int m=0;m<4;++m) acc[m]=(f32x4){0.f,0.f,0.f,0.f};
      #pragma unroll 4
      for(int kt=0;kt<32;++kt){
        short8 Bfr = *(const short8*)(bp + kt*32);
        #pragma unroll
        for(int m=0;m<4;++m){
          short8 Afr = cvt8(ap + (size_t)m*16*H_ + kt*32);
          acc[m] = mfma16(Afr, Bfr, acc[m]);
        }
      }
      const int b  = bs0 >> CHLOG_;
      const int sl = bs0 & (CH_-1);
      float* orow = out + ((size_t)b*S_ + (t0 - CH_) + sl)*512;
      #pragma unroll
      for(int m=0;m<4;++m){
        const int o0 = ot*64 + m*16 + qd*4;
        f32x4 ov;
        #pragma unroll
        for(int r=0;r<4;++r) ov[r] = acc[m][r] + obp[o0+r];
        *(f32x4*)(orow + o0) = ov;
      }
    }
  }
}

// ---------------------------------------------------------------------------
extern "C" void kernel_launch(void* const* d_in, const int* in_sizes, int n_in,
                              void* d_out, int out_size, void* d_ws, size_t ws_size,
                              hipStream_t stream)
{
  const float* x  = (const float*)d_in[0];
  const float* Wf = (const float*)d_in[1];
  const float* bf = (const float*)d_in[2];
  const float* Wi = (const float*)d_in[3];
  const float* bi = (const float*)d_in[4];
  const float* Wo = (const float*)d_in[5];
  const float* bo = (const float*)d_in[6];
  const float* Wc = (const float*)d_in[7];
  const float* bc = (const float*)d_in[8];
  const float* ow = (const float*)d_in[9];
  const float* ob = (const float*)d_in[10];
  float* out = (float*)d_out;

  // workspace layout (fits proven ws_size >= 151,178,240):
  //   flags @0        (8,192)
  //   cbuf  @8,192    (131,072)
  //   hs0   @139,264  (8,388,608)   [32][128][1024] bf16
  //   hs1   @8,527,872 (8,388,608)
  //   xg0   @16,916,480 (67,108,864) [128][4096][32] f32
  //   xg1   @84,025,344 (67,108,864)  -> end 151,134,208
  char* ws = (char*)d_ws;
  unsigned* flags = (unsigned*)ws;
  float* cbuf  = (float*)(ws + 8192);
  u16*   hsb[2] = { (u16*)(ws + 139264), (u16*)(ws + 8527872) };
  float* xgb[2] = { (float*)(ws + 16916480), (float*)(ws + 84025344) };
  float* hfin = out + (size_t)8388608;
  float* cfin = out + (size_t)8421376;

  // zero flags + cbuf + hs0 + hs1 (hs1 = zero h-carry for chunk 0)
  hipMemsetAsync(ws, 0, 16916480, stream);

  // prologue: xg for chunk 0 (verified kernel)
  k_xg<<<dim3(64, CH_/8), 256, 0, stream>>>(x, Wf, Wi, Wo, Wc, bf, bi, bo, bc, xgb[0], 0);

  for(int c=0; c<4; ++c){
    const float* a_xgc = xgb[c&1];
    float*       a_xgn = (c<3) ? xgb[(c+1)&1] : (float*)0;
    const u16*   a_hsp = hsb[(c+1)&1];
    u16*         a_hsc = hsb[c&1];
    int a_t0 = c*CH_;
    int a_do = (c>0) ? 1 : 0;
    void* args[] = { (void*)&x,
                     (void*)&Wf, (void*)&Wi, (void*)&Wo, (void*)&Wc,
                     (void*)&bf, (void*)&bi, (void*)&bo, (void*)&bc,
                     (void*)&ow, (void*)&ob,
                     (void*)&a_xgc, (void*)&a_xgn, (void*)&a_hsp, (void*)&a_hsc,
                     (void*)&hfin, (void*)&cfin, (void*)&cbuf, (void*)&flags,
                     (void*)&out, (void*)&a_t0, (void*)&a_do };
    hipLaunchCooperativeKernel((const void*)k_fused, dim3(NREC+NWRK), dim3(256), args, 0, stream);
  }

  // epilogue: out for chunk 3 (verified kernel)
  k_out<<<dim3(CH_/2, 8), 256, 0, stream>>>(hsb[1], ow, ob, out, 3*CH_, CHLOG_);
}

// Round 7
// 2828.588 us; speedup vs baseline: 1.3083x; 1.2883x over previous
//
#include <hip/hip_runtime.h>

typedef unsigned short u16;
typedef __attribute__((ext_vector_type(8))) short short8;
typedef __attribute__((ext_vector_type(4))) float f32x4;
typedef __attribute__((ext_vector_type(2))) float f32x2;

#define S_ 512
#define I_ 512
#define H_ 1024
#define B_ 32
#define G_ 4096   // 4*H
#define WROW 1536 // I+H
#define CH_ 128
#define CHLOG_ 7
#define NREC 64
#define NWRK 192  // grid = 256 total: unconditional co-residency (1 block/CU)

__device__ __forceinline__ u16 f2b(float f){ union{float f;unsigned u;}c; c.f=f; unsigned u=c.u; return (u16)((u + 0x7FFFu + ((u>>16)&1u))>>16); }

// trunc-pack two fp32 into two bf16 lanes (verified pattern; NOT v_perm)
__device__ __forceinline__ unsigned pk2(float a, float b){
  union{float f;unsigned u;} x, y; x.f=a; y.f=b;
  return (x.u>>16) | (y.u & 0xffff0000u);
}
__device__ __forceinline__ short8 cvt8(const float* __restrict__ p){
  f32x4 a = *(const f32x4*)p;
  f32x4 b = *(const f32x4*)(p+4);
  union{unsigned u[4]; short8 s;} r;
  r.u[0]=pk2(a[0],a[1]); r.u[1]=pk2(a[2],a[3]);
  r.u[2]=pk2(b[0],b[1]); r.u[3]=pk2(b[2],b[3]);
  return r.s;
}
__device__ __forceinline__ short8 cvt8r(f32x4 a, f32x4 b){
  union{unsigned u[4]; short8 s;} r;
  r.u[0]=pk2(a[0],a[1]); r.u[1]=pk2(a[2],a[3]);
  r.u[2]=pk2(b[0],b[1]); r.u[3]=pk2(b[2],b[3]);
  return r.s;
}
__device__ __forceinline__ f32x4 mfma16(short8 a, short8 b, f32x4 c){
  return __builtin_amdgcn_mfma_f32_16x16x32_bf16(a,b,c,0,0,0);
}
__device__ __forceinline__ float sigf(float x){ return 1.0f/(1.0f+__expf(-x)); }
__device__ __forceinline__ float tanhfast(float x){ return 1.0f - 2.0f/(__expf(2.0f*x)+1.0f); }

// ---------------------------------------------------------------------------
// Standalone k_xg (PROLOGUE only, chunk 0) — verbatim verified kernel.
// ---------------------------------------------------------------------------
__global__ __launch_bounds__(256,2) void k_xg(
    const float* __restrict__ x,
    const float* __restrict__ Wf, const float* __restrict__ Wi,
    const float* __restrict__ Wo, const float* __restrict__ Wc,
    const float* __restrict__ bfp, const float* __restrict__ bip,
    const float* __restrict__ bop, const float* __restrict__ bcp,
    float* __restrict__ xg, int t0)
{
  const int gt = blockIdx.x;
  const int sg = blockIdx.y;
  const int wv = threadIdx.x>>6;
  const int ln = threadIdx.x&63;
  const int n16 = ln&15, qd = ln>>4;
  const int g0 = gt*64 + wv*16;
  const int q = g0>>10, j0 = g0&1023;
  const float* W  = (q==0)?Wf:(q==1)?Wi:(q==2)?Wo:Wc;
  const float* bb = (q==0)?bfp:(q==1)?bip:(q==2)?bop:bcp;

  short8 Bw[16];
  {
    const float* wr = W + (size_t)(j0+n16)*WROW + qd*8;
    #pragma unroll
    for(int kt=0;kt<16;++kt) Bw[kt] = cvt8(wr + kt*32);
  }
  const float bv = bb[j0+n16];

  for(int si=0; si<8; ++si){
    const int sl = sg*8 + si;
    const int s  = t0 + sl;
    const float* xp = x + (size_t)n16*(S_*I_) + (size_t)s*I_ + qd*8;
    f32x4 a0={0,0,0,0}, a1={0,0,0,0};
    #pragma unroll
    for(int kt=0;kt<16;++kt){
      short8 A0 = cvt8(xp + kt*32);
      short8 A1 = cvt8(xp + (size_t)16*(S_*I_) + kt*32);
      a0 = mfma16(A0, Bw[kt], a0);
      a1 = mfma16(A1, Bw[kt], a1);
    }
    float* op = xg + ((size_t)sl*G_ + g0 + n16)*B_ + qd*4;
    f32x4 o0, o1;
    #pragma unroll
    for(int r=0;r<4;++r){ o0[r]=a0[r]+bv; o1[r]=a1[r]+bv; }
    *(f32x4*)op = o0;
    *(f32x4*)(op+16) = o1;
  }
}

// ---------------------------------------------------------------------------
// Standalone k_out (EPILOGUE only, last chunk) — verbatim verified kernel.
// ---------------------------------------------------------------------------
__global__ __launch_bounds__(256,2) void k_out(
  const u16* __restrict__ hs,
  const float* __restrict__ ow,
  const float* __restrict__ obp,
  float* __restrict__ out, int t0, int chlog)
{
  const int bst = blockIdx.x;
  const int ot  = blockIdx.y;
  const int wv = threadIdx.x>>6;
  const int ln = threadIdx.x&63;
  const int n16 = ln&15, qd = ln>>4;
  const int bs0 = bst*64 + wv*16 + n16;
  const u16* bp   = hs + (size_t)bs0*H_ + qd*8;
  const float* ap = ow + (size_t)(ot*64 + n16)*H_ + qd*8;
  f32x4 acc[4];
  #pragma unroll
  for(int m=0;m<4;++m) acc[m]=(f32x4){0.f,0.f,0.f,0.f};
  #pragma unroll 4
  for(int kt=0;kt<32;++kt){
    short8 Bfr = *(const short8*)(bp + kt*32);
    #pragma unroll
    for(int m=0;m<4;++m){
      short8 Afr = cvt8(ap + (size_t)m*16*H_ + kt*32);
      acc[m] = mfma16(Afr, Bfr, acc[m]);
    }
  }
  const int b  = bs0 >> chlog;
  const int sl = bs0 & ((1<<chlog)-1);
  float* orow = out + ((size_t)b*S_ + t0 + sl)*512;
  #pragma unroll
  for(int m=0;m<4;++m){
    const int o0 = ot*64 + m*16 + qd*4;
    f32x4 ov;
    #pragma unroll
    for(int r=0;r<4;++r) ov[r] = acc[m][r] + obp[o0+r];
    *(f32x4*)(orow + o0) = ov;
  }
}

// ---------------------------------------------------------------------------
// k_fused: cooperative dispatch for chunk c. Grid 256 (64 rec + 192 workers).
//   blocks 0..63   : R0-verified k_rec body — UNCHANGED from R6 (passed).
//   blocks 64..255 : workers, R7 change: same verified tile MATH, but
//     (a) explicit 2-stage load batching (stage 32 f32x4 in flight, then
//         cvt+MFMA) — fixes the 1-wave/SIMD load-use serialization that
//         made tiles cost 86us in R6;
//     (b) fixed-gt mapping with Bw hoisted out of the tile loop.
//   All rec<->worker dependencies still cross dispatch boundaries only.
// ---------------------------------------------------------------------------
__global__ __launch_bounds__(256,1) void k_fused(
  const float* __restrict__ x,
  const float* __restrict__ Wf, const float* __restrict__ Wi,
  const float* __restrict__ Wo, const float* __restrict__ Wc,
  const float* __restrict__ bfp, const float* __restrict__ bip,
  const float* __restrict__ bop, const float* __restrict__ bcp,
  const float* __restrict__ ow, const float* __restrict__ obp,
  const float* __restrict__ xg_cur,  // [CH_][4096][32] this chunk
  float* __restrict__ xg_next,       // next chunk (null on last)
  const u16* __restrict__ hs_prev,   // [32][CH_][1024] prev chunk
  u16* __restrict__ hs_cur,          // [32][CH_][1024] this chunk
  float* __restrict__ hfin, float* __restrict__ cfin,
  float* __restrict__ cbuf,          // [32][1024] f32 c carry
  unsigned* __restrict__ flags,      // 64 x u32, 128B apart, monotone abs-t
  float* __restrict__ out,
  int t0, int do_out)
{
  const int bid = blockIdx.x;
  const int tid = threadIdx.x;
  __shared__ float pbuf[4][4][16][38]; // rec only

  if (bid < NREC){
    // ---------------- recurrence (verified body, UNCHANGED) ----------------
    const int h0  = bid*16;
    const int kw  = tid>>6;
    const int ln  = tid&63;
    const int n16 = ln&15, qd = ln>>4;

    short8 Bf[4][8];
    {
      const int kcol = 512 + kw*256 + qd*8;
      const float* w0 = Wf + (size_t)(h0+n16)*WROW + kcol;
      const float* w1 = Wi + (size_t)(h0+n16)*WROW + kcol;
      const float* w2 = Wo + (size_t)(h0+n16)*WROW + kcol;
      const float* w3 = Wc + (size_t)(h0+n16)*WROW + kcol;
      #pragma unroll
      for(int k=0;k<8;++k){
        Bf[0][k] = cvt8(w0 + k*32);
        Bf[1][k] = cvt8(w1 + k*32);
        Bf[2][k] = cvt8(w2 + k*32);
        Bf[3][k] = cvt8(w3 + k*32);
      }
    }
    const int ub  = tid>>3;
    const int hi0 = (tid&7)*2;
    f32x2 c01 = *(const f32x2*)(cbuf + (size_t)ub*H_ + h0 + hi0);

    for(int tl=0; tl<CH_; ++tl){
      const int t = t0 + tl;
      float xv[2][4];
      {
        const float* xp = xg_cur + ((size_t)tl*G_ + h0 + hi0)*B_ + ub;
        #pragma unroll
        for(int q=0;q<4;++q){
          xv[0][q] = xp[(size_t)q*1024*B_];
          xv[1][q] = xp[(size_t)q*1024*B_ + B_];
        }
      }
      if (t>0){
        if (tid < 64){
          const unsigned goal = (unsigned)t;
          unsigned v;
          do {
            v = __hip_atomic_load(flags + (tid<<5), __ATOMIC_RELAXED, __HIP_MEMORY_SCOPE_AGENT);
            if (__ballot(v < goal) == 0ull) break;
            __builtin_amdgcn_s_sleep(1);
          } while (true);
          // no fence needed: hs[tl-1] lines are first-touch-after-flag
        }
        __syncthreads();
      }
      const u16* hbase; size_t bstride;
      if (tl==0){ hbase = hs_prev + (size_t)(CH_-1)*H_; bstride = (size_t)CH_*H_; }
      else      { hbase = hs_cur  + (size_t)(tl-1)*H_;  bstride = (size_t)CH_*H_; }
      const int kcolq = kw*256 + qd*8;
      const u16* hp0 = hbase + (size_t)n16*bstride      + kcolq;
      const u16* hp1 = hbase + (size_t)(16+n16)*bstride + kcolq;
      f32x4 acc[2][4];
      #pragma unroll
      for(int m=0;m<2;++m)
        #pragma unroll
        for(int q=0;q<4;++q) acc[m][q]=(f32x4){0.f,0.f,0.f,0.f};
      #pragma unroll
      for(int k=0;k<8;++k){
        short8 A0 = *(const short8*)(hp0 + k*32);
        short8 A1 = *(const short8*)(hp1 + k*32);
        #pragma unroll
        for(int q=0;q<4;++q){
          acc[0][q] = mfma16(A0, Bf[q][k], acc[0][q]);
          acc[1][q] = mfma16(A1, Bf[q][k], acc[1][q]);
        }
      }
      #pragma unroll
      for(int m=0;m<2;++m)
        #pragma unroll
        for(int q=0;q<4;++q){
          float* dst = &pbuf[kw][q][n16][m*16 + qd*4];
          *(f32x2*)dst       = (f32x2){acc[m][q][0], acc[m][q][1]};
          *(f32x2*)(dst + 2) = (f32x2){acc[m][q][2], acc[m][q][3]};
        }
      __syncthreads();
      float g[2][4];
      #pragma unroll
      for(int e=0;e<2;++e){
        #pragma unroll
        for(int q=0;q<4;++q){
          g[e][q] = xv[e][q] + pbuf[0][q][hi0+e][ub] + pbuf[1][q][hi0+e][ub]
                             + pbuf[2][q][hi0+e][ub] + pbuf[3][q][hi0+e][ub];
        }
      }
      float hv[2], cn[2];
      #pragma unroll
      for(int e=0;e<2;++e){
        float fg = sigf(g[e][0]);
        float ig = sigf(g[e][1]);
        float og = sigf(g[e][2]);
        float ch = tanhfast(g[e][3]);
        cn[e] = fg*c01[e] + ig*ch;
        hv[e] = og*tanhfast(cn[e]);
        c01[e] = cn[e];
      }
      const unsigned hpk = (unsigned)f2b(hv[0]) | ((unsigned)f2b(hv[1])<<16);
      unsigned* hw = (unsigned*)(hs_cur + ((size_t)ub*CH_ + tl)*H_ + h0 + hi0);
      __hip_atomic_store(hw, hpk, __ATOMIC_RELAXED, __HIP_MEMORY_SCOPE_AGENT);
      if (t==511){
        *(f32x2*)(hfin + (size_t)ub*H_ + h0 + hi0) = (f32x2){hv[0], hv[1]};
        *(f32x2*)(cfin + (size_t)ub*H_ + h0 + hi0) = (f32x2){cn[0], cn[1]};
      }
      if (tl==CH_-1)
        *(f32x2*)(cbuf + (size_t)ub*H_ + h0 + hi0) = c01;
      __syncthreads();              // vmcnt(0): hs stores ack'd at LLC
      if (tid==0)
        __hip_atomic_store(flags + (bid<<5), (unsigned)(t+1),
                           __ATOMIC_RELAXED, __HIP_MEMORY_SCOPE_AGENT);
    }
    return;
  }

  // ---------------- workers (R7: ILP-staged, fixed-gt) ----------------
  const int w  = bid - NREC;
  const int wv = tid>>6;
  const int ln = tid&63;
  const int n16 = ln&15, qd = ln>>4;

  if (xg_next){
    // xg tiles for chunk c+1: gt fixed per worker, sg walks by 3.
    const int gt = w & 63;
    const int g0 = gt*64 + wv*16;
    const int q = g0>>10, j0 = g0&1023;
    const float* W  = (q==0)?Wf:(q==1)?Wi:(q==2)?Wo:Wc;
    const float* bb = (q==0)?bfp:(q==1)?bip:(q==2)?bop:bcp;
    short8 Bw[16];   // hoisted: one load per worker (gt fixed)
    {
      const float* wr = W + (size_t)(j0+n16)*WROW + qd*8;
      #pragma unroll
      for(int kt=0;kt<16;++kt) Bw[kt] = cvt8(wr + kt*32);
    }
    const float bv = bb[j0+n16];
    for (int sg = w>>6; sg < 16; sg += 3){
      for(int si=0; si<8; ++si){
        const int sl = sg*8 + si;
        const int s  = t0 + CH_ + sl;
        const float* xp = x + (size_t)n16*(S_*I_) + (size_t)s*I_ + qd*8;
        f32x4 a0={0,0,0,0}, a1={0,0,0,0};
        #pragma unroll
        for(int h=0;h<2;++h){
          // stage: 32 loads in flight (the R6 version serialized these)
          f32x4 pa[8][2], pb[8][2];
          #pragma unroll
          for(int k8=0;k8<8;++k8){
            const int kt = h*8 + k8;
            pa[k8][0] = *(const f32x4*)(xp + kt*32);
            pa[k8][1] = *(const f32x4*)(xp + kt*32 + 4);
            pb[k8][0] = *(const f32x4*)(xp + (size_t)16*(S_*I_) + kt*32);
            pb[k8][1] = *(const f32x4*)(xp + (size_t)16*(S_*I_) + kt*32 + 4);
          }
          #pragma unroll
          for(int k8=0;k8<8;++k8){
            const int kt = h*8 + k8;
            a0 = mfma16(cvt8r(pa[k8][0], pa[k8][1]), Bw[kt], a0);
            a1 = mfma16(cvt8r(pb[k8][0], pb[k8][1]), Bw[kt], a1);
          }
        }
        float* op = xg_next + ((size_t)sl*G_ + g0 + n16)*B_ + qd*4;
        f32x4 o0, o1;
        #pragma unroll
        for(int r=0;r<4;++r){ o0[r]=a0[r]+bv; o1[r]=a1[r]+bv; }
        *(f32x4*)op = o0;
        *(f32x4*)(op+16) = o1;
      }
    }
  }

  if (do_out){
    // out tiles for chunk c-1 (reads hs_prev written LAST dispatch)
    for (int tau = w; tau < 512; tau += NWRK){
      const int bst = tau & 63, ot = tau >> 6;
      const int bs0 = bst*64 + wv*16 + n16;
      const u16* bp   = hs_prev + (size_t)bs0*H_ + qd*8;
      const float* ap = ow + (size_t)(ot*64 + n16)*H_ + qd*8;
      f32x4 acc[4];
      #pragma unroll
      for(int m=0;m<4;++m) acc[m]=(f32x4){0.f,0.f,0.f,0.f};
      #pragma unroll
      for(int g=0;g<8;++g){
        short8 hbf[4];
        f32x4 wa[4][4][2];  // staged: 4 hs + 32 ow loads in flight
        #pragma unroll
        for(int k4=0;k4<4;++k4){
          const int kt = g*4 + k4;
          hbf[k4] = *(const short8*)(bp + kt*32);
          #pragma unroll
          for(int m=0;m<4;++m){
            wa[k4][m][0] = *(const f32x4*)(ap + (size_t)m*16*H_ + kt*32);
            wa[k4][m][1] = *(const f32x4*)(ap + (size_t)m*16*H_ + kt*32 + 4);
          }
        }
        #pragma unroll
        for(int k4=0;k4<4;++k4)
          #pragma unroll
          for(int m=0;m<4;++m)
            acc[m] = mfma16(cvt8r(wa[k4][m][0], wa[k4][m][1]), hbf[k4], acc[m]);
      }
      const int b  = bs0 >> CHLOG_;
      const int sl = bs0 & (CH_-1);
      float* orow = out + ((size_t)b*S_ + (t0 - CH_) + sl)*512;
      #pragma unroll
      for(int m=0;m<4;++m){
        const int o0 = ot*64 + m*16 + qd*4;
        f32x4 ov;
        #pragma unroll
        for(int r=0;r<4;++r) ov[r] = acc[m][r] + obp[o0+r];
        *(f32x4*)(orow + o0) = ov;
      }
    }
  }
}

// ---------------------------------------------------------------------------
extern "C" void kernel_launch(void* const* d_in, const int* in_sizes, int n_in,
                              void* d_out, int out_size, void* d_ws, size_t ws_size,
                              hipStream_t stream)
{
  const float* x  = (const float*)d_in[0];
  const float* Wf = (const float*)d_in[1];
  const float* bf = (const float*)d_in[2];
  const float* Wi = (const float*)d_in[3];
  const float* bi = (const float*)d_in[4];
  const float* Wo = (const float*)d_in[5];
  const float* bo = (const float*)d_in[6];
  const float* Wc = (const float*)d_in[7];
  const float* bc = (const float*)d_in[8];
  const float* ow = (const float*)d_in[9];
  const float* ob = (const float*)d_in[10];
  float* out = (float*)d_out;

  // workspace layout (fits proven ws_size >= 151,178,240):
  //   flags @0        (8,192)
  //   cbuf  @8,192    (131,072)
  //   hs0   @139,264  (8,388,608)   [32][128][1024] bf16
  //   hs1   @8,527,872 (8,388,608)
  //   xg0   @16,916,480 (67,108,864) [128][4096][32] f32
  //   xg1   @84,025,344 (67,108,864)  -> end 151,134,208
  char* ws = (char*)d_ws;
  unsigned* flags = (unsigned*)ws;
  float* cbuf  = (float*)(ws + 8192);
  u16*   hsb[2] = { (u16*)(ws + 139264), (u16*)(ws + 8527872) };
  float* xgb[2] = { (float*)(ws + 16916480), (float*)(ws + 84025344) };
  float* hfin = out + (size_t)8388608;
  float* cfin = out + (size_t)8421376;

  // zero flags + cbuf + hs0 + hs1 (hs1 = zero h-carry for chunk 0)
  hipMemsetAsync(ws, 0, 16916480, stream);

  // prologue: xg for chunk 0 (verified kernel)
  k_xg<<<dim3(64, CH_/8), 256, 0, stream>>>(x, Wf, Wi, Wo, Wc, bf, bi, bo, bc, xgb[0], 0);

  for(int c=0; c<4; ++c){
    const float* a_xgc = xgb[c&1];
    float*       a_xgn = (c<3) ? xgb[(c+1)&1] : (float*)0;
    const u16*   a_hsp = hsb[(c+1)&1];
    u16*         a_hsc = hsb[c&1];
    int a_t0 = c*CH_;
    int a_do = (c>0) ? 1 : 0;
    void* args[] = { (void*)&x,
                     (void*)&Wf, (void*)&Wi, (void*)&Wo, (void*)&Wc,
                     (void*)&bf, (void*)&bi, (void*)&bo, (void*)&bc,
                     (void*)&ow, (void*)&ob,
                     (void*)&a_xgc, (void*)&a_xgn, (void*)&a_hsp, (void*)&a_hsc,
                     (void*)&hfin, (void*)&cfin, (void*)&cbuf, (void*)&flags,
                     (void*)&out, (void*)&a_t0, (void*)&a_do };
    hipLaunchCooperativeKernel((const void*)k_fused, dim3(NREC+NWRK), dim3(256), args, 0, stream);
  }

  // epilogue: out for chunk 3 (verified kernel)
  k_out<<<dim3(CH_/2, 8), 256, 0, stream>>>(hsb[1], ow, ob, out, 3*CH_, CHLOG_);
}